// Round 1
// baseline (9085.489 us; speedup 1.0000x reference)
//
#include <hip/hip_runtime.h>
#include <math.h>

#define NBATCH 8
#define NTOK   4096
#define DIMX   512
#define QKVC   1536   // 3*8*64
#define DH     64
#define SCALE  0.125f // 64^-0.5

// ================= QKV GEMM: qkv[32768][1536] = x[32768][512] @ w[512][1536] =================
#define BM 128
#define BN 128
#define BK 16

__global__ __launch_bounds__(256) void qkv_gemm(const float* __restrict__ X,
                                                const float* __restrict__ W,
                                                float* __restrict__ QKV) {
    __shared__ float As[BK][BM + 4];  // pad: store-side conflicts -> 2-way (free)
    __shared__ float Bs[BK][BN + 4];
    const int t  = threadIdx.x;
    const int tx = t & 15, ty = t >> 4;
    const int bm = blockIdx.x & 255;   // 32768/128 = 256 row-tiles
    const int bn = blockIdx.x >> 8;    // 1536/128  = 12 col-tiles
    const int m0 = bm * BM, n0 = bn * BN;

    float acc[8][8];
#pragma unroll
    for (int i = 0; i < 8; ++i)
#pragma unroll
        for (int j = 0; j < 8; ++j) acc[i][j] = 0.f;

    const int ar  = t >> 2, ak = (t & 3) << 2;   // A: rows ar, ar+64; k-offset ak..ak+3
    const int bkr = t >> 5, bc = (t & 31) << 2;  // B: k-rows bkr, bkr+8; cols bc..bc+3

    const float* Xp = X + (size_t)m0 * DIMX;
    const float* Wp = W + n0;

    for (int k0 = 0; k0 < DIMX; k0 += BK) {
        float4 a0 = *(const float4*)(Xp + (size_t)ar * DIMX + k0 + ak);
        float4 a1 = *(const float4*)(Xp + (size_t)(ar + 64) * DIMX + k0 + ak);
        float4 b0 = *(const float4*)(Wp + (size_t)(k0 + bkr) * QKVC + bc);
        float4 b1 = *(const float4*)(Wp + (size_t)(k0 + bkr + 8) * QKVC + bc);
        __syncthreads();  // previous iteration's compute done before overwrite
        As[ak+0][ar]    = a0.x; As[ak+1][ar]    = a0.y; As[ak+2][ar]    = a0.z; As[ak+3][ar]    = a0.w;
        As[ak+0][ar+64] = a1.x; As[ak+1][ar+64] = a1.y; As[ak+2][ar+64] = a1.z; As[ak+3][ar+64] = a1.w;
        *(float4*)&Bs[bkr][bc]     = b0;
        *(float4*)&Bs[bkr + 8][bc] = b1;
        __syncthreads();
#pragma unroll
        for (int kk = 0; kk < BK; ++kk) {
            float a[8], bb[8];
            *(float4*)&a[0]  = *(const float4*)&As[kk][ty * 4];
            *(float4*)&a[4]  = *(const float4*)&As[kk][64 + ty * 4];
            *(float4*)&bb[0] = *(const float4*)&Bs[kk][tx * 4];
            *(float4*)&bb[4] = *(const float4*)&Bs[kk][64 + tx * 4];
#pragma unroll
            for (int i = 0; i < 8; ++i)
#pragma unroll
                for (int j = 0; j < 8; ++j) acc[i][j] = fmaf(a[i], bb[j], acc[i][j]);
        }
    }
#pragma unroll
    for (int i = 0; i < 8; ++i) {
        int r = m0 + ((i < 4) ? (ty * 4 + i) : (64 + ty * 4 + i - 4));
        float* o = QKV + (size_t)r * QKVC + n0;
        *(float4*)(o + tx * 4)      = make_float4(acc[i][0], acc[i][1], acc[i][2], acc[i][3]);
        *(float4*)(o + 64 + tx * 4) = make_float4(acc[i][4], acc[i][5], acc[i][6], acc[i][7]);
    }
}

// ================= Spatial attention: heads 0..3, per frame (nt) over 256 tokens ==============
// One query row per thread (256 rows/block). K staged fully (64 KiB); V double-buffered
// in 32-key chunks (16 KiB). Online softmax is entirely thread-local (no cross-lane).
#define SCHK 32
__global__ __launch_bounds__(256, 2) void attn_spatial(const float* __restrict__ QKV,
                                                       float* __restrict__ Out) {
    __shared__ float Ks[256][DH];
    __shared__ float Vs[2][SCHK][DH];
    const int t    = threadIdx.x;
    const int nt   = blockIdx.x & 15;
    const int h    = (blockIdx.x >> 4) & 3;
    const int b    = blockIdx.x >> 6;
    const int base = nt * 256;
    const size_t rowoff = (size_t)b * NTOK;

    const float* Kg = QKV + (rowoff + base) * QKVC + 512  + h * DH;
    const float* Vg = QKV + (rowoff + base) * QKVC + 1024 + h * DH;
    const float* Qg = QKV + (rowoff + base + t) * QKVC + h * DH;

    // stage K tile [256][64] (coalesced: 16 lanes per row)
#pragma unroll
    for (int i = 0; i < 16; ++i) {
        int idx = t + 256 * i;
        int r = idx >> 4, c4 = (idx & 15) << 2;
        *(float4*)&Ks[r][c4] = *(const float4*)(Kg + (size_t)r * QKVC + c4);
    }
    // stage V chunk 0
#pragma unroll
    for (int i = 0; i < 2; ++i) {
        int idx = t + 256 * i;
        int r = idx >> 4, c4 = (idx & 15) << 2;
        *(float4*)&Vs[0][r][c4] = *(const float4*)(Vg + (size_t)r * QKVC + c4);
    }
    float q[DH];
#pragma unroll
    for (int c = 0; c < DH; c += 4) *(float4*)&q[c] = *(const float4*)(Qg + c);

    float acc[DH];
#pragma unroll
    for (int c = 0; c < DH; ++c) acc[c] = 0.f;
    float m = -INFINITY, l = 0.f;

    __syncthreads();

    for (int ch = 0; ch < 8; ++ch) {
        float s[SCHK];
        float cmax = -INFINITY;
#pragma unroll
        for (int j = 0; j < SCHK; ++j) {
            const float* kr = &Ks[ch * SCHK + j][0];  // uniform j across block -> LDS broadcast
            float d = 0.f;
#pragma unroll
            for (int c = 0; c < DH; c += 4) {
                float4 kv = *(const float4*)&kr[c];
                d = fmaf(q[c], kv.x, d); d = fmaf(q[c+1], kv.y, d);
                d = fmaf(q[c+2], kv.z, d); d = fmaf(q[c+3], kv.w, d);
            }
            s[j] = d * SCALE;
            cmax = fmaxf(cmax, s[j]);
        }
        float mn   = fmaxf(m, cmax);
        float corr = __expf(m - mn);   // first chunk: exp(-inf)=0, acc already 0
        float psum = 0.f;
#pragma unroll
        for (int j = 0; j < SCHK; ++j) { s[j] = __expf(s[j] - mn); psum += s[j]; }
        l = l * corr + psum;
        m = mn;
#pragma unroll
        for (int c = 0; c < DH; ++c) acc[c] *= corr;

        // prefetch next V chunk into regs (hide HBM latency under PV)
        float4 v0, v1;
        if (ch + 1 < 8) {
            int r0 = t >> 4,          c0 = (t & 15) << 2;
            int r1 = (t + 256) >> 4,  c1 = c0;
            v0 = *(const float4*)(Vg + (size_t)((ch + 1) * SCHK + r0) * QKVC + c0);
            v1 = *(const float4*)(Vg + (size_t)((ch + 1) * SCHK + r1) * QKVC + c1);
        }
        // PV accumulate
#pragma unroll
        for (int j = 0; j < SCHK; ++j) {
            const float* vr = &Vs[ch & 1][j][0];
            float p = s[j];
#pragma unroll
            for (int c = 0; c < DH; c += 4) {
                float4 vv = *(const float4*)&vr[c];
                acc[c]   = fmaf(p, vv.x, acc[c]);   acc[c+1] = fmaf(p, vv.y, acc[c+1]);
                acc[c+2] = fmaf(p, vv.z, acc[c+2]); acc[c+3] = fmaf(p, vv.w, acc[c+3]);
            }
        }
        if (ch + 1 < 8) {
            int r0 = t >> 4, c0 = (t & 15) << 2;
            int r1 = (t + 256) >> 4;
            *(float4*)&Vs[(ch + 1) & 1][r0][c0] = v0;
            *(float4*)&Vs[(ch + 1) & 1][r1][c0] = v1;
        }
        __syncthreads();
    }

    float inv = 1.f / l;
    float* op = Out + ((size_t)(b * 4 + h) * NTOK + base + t) * DH;
#pragma unroll
    for (int c = 0; c < DH; c += 4)
        *(float4*)(op + c) = make_float4(acc[c]*inv, acc[c+1]*inv, acc[c+2]*inv, acc[c+3]*inv);
}

// ================= Temporal attention: heads 4..7, per spatial pos over 16 frames =============
// token axis viewed as (s=256, NT=16): keys for row (b,h,s) are the 16 CONTIGUOUS tokens
// s*16..s*16+15. One row/thread; 16-lane groups share keys -> identical addrs merge in HW.
__global__ __launch_bounds__(256) void attn_temporal(const float* __restrict__ QKV,
                                                     float* __restrict__ Out) {
    const int rid   = blockIdx.x * 256 + threadIdx.x;
    const int tt    = rid & 15;
    const int s     = (rid >> 4) & 255;
    const int h     = (rid >> 12) & 3;
    const int b     = rid >> 14;
    const int head  = 4 + h;                 // second half of heads
    const int token = s * 16 + tt;
    const size_t rowoff = (size_t)b * NTOK;

    const float* Qp = QKV + (rowoff + token) * QKVC + head * DH;
    const float* Kb = QKV + (rowoff + s * 16) * QKVC + 512  + head * DH;
    const float* Vb = QKV + (rowoff + s * 16) * QKVC + 1024 + head * DH;

    float q[DH];
#pragma unroll
    for (int c = 0; c < DH; c += 4) *(float4*)&q[c] = *(const float4*)(Qp + c);

    float sc[16];
    float mx = -INFINITY;
#pragma unroll
    for (int j = 0; j < 16; ++j) {
        const float* kr = Kb + (size_t)j * QKVC;
        float d = 0.f;
#pragma unroll
        for (int c = 0; c < DH; c += 4) {
            float4 kv = *(const float4*)(kr + c);
            d = fmaf(q[c], kv.x, d); d = fmaf(q[c+1], kv.y, d);
            d = fmaf(q[c+2], kv.z, d); d = fmaf(q[c+3], kv.w, d);
        }
        sc[j] = d * SCALE;
        mx = fmaxf(mx, sc[j]);
    }
    float l = 0.f;
#pragma unroll
    for (int j = 0; j < 16; ++j) { sc[j] = __expf(sc[j] - mx); l += sc[j]; }
    float inv = 1.f / l;

    float acc[DH];
#pragma unroll
    for (int c = 0; c < DH; ++c) acc[c] = 0.f;
#pragma unroll
    for (int j = 0; j < 16; ++j) {
        const float* vr = Vb + (size_t)j * QKVC;
        float p = sc[j];
#pragma unroll
        for (int c = 0; c < DH; c += 4) {
            float4 vv = *(const float4*)(vr + c);
            acc[c]   = fmaf(p, vv.x, acc[c]);   acc[c+1] = fmaf(p, vv.y, acc[c+1]);
            acc[c+2] = fmaf(p, vv.z, acc[c+2]); acc[c+3] = fmaf(p, vv.w, acc[c+3]);
        }
    }
    float* op = Out + (size_t)(NBATCH * 4) * NTOK * DH          // branch-1 (temporal) offset
                    + ((size_t)(b * 4 + h) * NTOK + token) * DH;
#pragma unroll
    for (int c = 0; c < DH; c += 4)
        *(float4*)(op + c) = make_float4(acc[c]*inv, acc[c+1]*inv, acc[c+2]*inv, acc[c+3]*inv);
}

extern "C" void kernel_launch(void* const* d_in, const int* in_sizes, int n_in,
                              void* d_out, int out_size, void* d_ws, size_t ws_size,
                              hipStream_t stream) {
    const float* x = (const float*)d_in[0];   // [8,4096,512] fp32
    const float* w = (const float*)d_in[1];   // [512,1536]  fp32
    float* out = (float*)d_out;               // [2,8,4,4096,64] fp32
    float* qkv = (float*)d_ws;                // needs 8*4096*1536*4 = 192 MiB scratch

    qkv_gemm<<<dim3(256 * 12), 256, 0, stream>>>(x, w, qkv);
    attn_spatial<<<dim3(512), 256, 0, stream>>>(qkv, out);
    attn_temporal<<<dim3(512), 256, 0, stream>>>(qkv, out);
}

// Round 2
// 1841.429 us; speedup vs baseline: 4.9339x; 4.9339x over previous
//
#include <hip/hip_runtime.h>
#include <math.h>

#define NBATCH 8
#define NTOK   4096
#define DIMX   512
#define QKVC   1536   // 3*8*64
#define DH     64
#define SCALE  0.125f // 64^-0.5

// ================= QKV GEMM: qkv[32768][1536] = x[32768][512] @ w[512][1536] =================
#define BM 128
#define BN 128
#define BK 16

__global__ __launch_bounds__(256) void qkv_gemm(const float* __restrict__ X,
                                                const float* __restrict__ W,
                                                float* __restrict__ QKV) {
    __shared__ float As[BK][BM + 4];
    __shared__ float Bs[BK][BN + 4];
    const int t  = threadIdx.x;
    const int tx = t & 15, ty = t >> 4;
    const int bm = blockIdx.x & 255;   // 32768/128 = 256 row-tiles
    const int bn = blockIdx.x >> 8;    // 1536/128  = 12 col-tiles
    const int m0 = bm * BM, n0 = bn * BN;

    float acc[8][8];
#pragma unroll
    for (int i = 0; i < 8; ++i)
#pragma unroll
        for (int j = 0; j < 8; ++j) acc[i][j] = 0.f;

    const int ar  = t >> 2, ak = (t & 3) << 2;
    const int bkr = t >> 5, bc = (t & 31) << 2;

    const float* Xp = X + (size_t)m0 * DIMX;
    const float* Wp = W + n0;

    for (int k0 = 0; k0 < DIMX; k0 += BK) {
        float4 a0 = *(const float4*)(Xp + (size_t)ar * DIMX + k0 + ak);
        float4 a1 = *(const float4*)(Xp + (size_t)(ar + 64) * DIMX + k0 + ak);
        float4 b0 = *(const float4*)(Wp + (size_t)(k0 + bkr) * QKVC + bc);
        float4 b1 = *(const float4*)(Wp + (size_t)(k0 + bkr + 8) * QKVC + bc);
        __syncthreads();
        As[ak+0][ar]    = a0.x; As[ak+1][ar]    = a0.y; As[ak+2][ar]    = a0.z; As[ak+3][ar]    = a0.w;
        As[ak+0][ar+64] = a1.x; As[ak+1][ar+64] = a1.y; As[ak+2][ar+64] = a1.z; As[ak+3][ar+64] = a1.w;
        *(float4*)&Bs[bkr][bc]     = b0;
        *(float4*)&Bs[bkr + 8][bc] = b1;
        __syncthreads();
#pragma unroll
        for (int kk = 0; kk < BK; ++kk) {
            float a[8], bb[8];
            *(float4*)&a[0]  = *(const float4*)&As[kk][ty * 4];
            *(float4*)&a[4]  = *(const float4*)&As[kk][64 + ty * 4];
            *(float4*)&bb[0] = *(const float4*)&Bs[kk][tx * 4];
            *(float4*)&bb[4] = *(const float4*)&Bs[kk][64 + tx * 4];
#pragma unroll
            for (int i = 0; i < 8; ++i)
#pragma unroll
                for (int j = 0; j < 8; ++j) acc[i][j] = fmaf(a[i], bb[j], acc[i][j]);
        }
    }
#pragma unroll
    for (int i = 0; i < 8; ++i) {
        int r = m0 + ((i < 4) ? (ty * 4 + i) : (64 + ty * 4 + i - 4));
        float* o = QKV + (size_t)r * QKVC + n0;
        *(float4*)(o + tx * 4)      = make_float4(acc[i][0], acc[i][1], acc[i][2], acc[i][3]);
        *(float4*)(o + 64 + tx * 4) = make_float4(acc[i][4], acc[i][5], acc[i][6], acc[i][7]);
    }
}

// ================= Spatial attention: heads 0..3, per frame (nt) over 256 tokens ==============
// 4 lanes per query row (lane l owns dims l*16..l*16+15) -> per-thread state is
// q[16]+acc[16]+s[32] ~ 90 VGPRs, no spill (round-1 failure mode: one row/thread
// needed 170+ floats, spilled to scratch -> 25 GB HBM traffic, 8.5 ms).
// Block = 256 threads = 64 rows; K tile fully staged (64 KiB); V double-buffered
// per 32-key chunk (16 KiB). Score dot reduced across the quad via 2x shfl_xor.
#define SCHK 32
__global__ __launch_bounds__(256) void attn_spatial(const float* __restrict__ QKV,
                                                    float* __restrict__ Out) {
    __shared__ float Ks[256][DH];
    __shared__ float Vs[2][SCHK][DH];
    const int t       = threadIdx.x;
    const int quarter = blockIdx.x & 3;
    const int nt      = (blockIdx.x >> 2) & 15;
    const int h       = (blockIdx.x >> 6) & 3;
    const int b       = blockIdx.x >> 8;
    const int base    = nt * 256;
    const int l       = t & 3;        // dim-slice within the quad
    const int r       = t >> 2;       // local query row 0..63
    const int row     = quarter * 64 + r;
    const size_t rowoff = (size_t)b * NTOK;

    const float* Kg = QKV + (rowoff + base) * QKVC + 512  + h * DH;
    const float* Vg = QKV + (rowoff + base) * QKVC + 1024 + h * DH;
    const float* Qg = QKV + (rowoff + base + row) * QKVC + h * DH + l * 16;

    // stage K tile [256][64] (coalesced: 16 lanes per row)
#pragma unroll
    for (int i = 0; i < 16; ++i) {
        int idx = t + 256 * i;
        int kr = idx >> 4, c4 = (idx & 15) << 2;
        *(float4*)&Ks[kr][c4] = *(const float4*)(Kg + (size_t)kr * QKVC + c4);
    }
    // stage V chunk 0
#pragma unroll
    for (int i = 0; i < 2; ++i) {
        int idx = t + 256 * i;
        int vr = idx >> 4, c4 = (idx & 15) << 2;
        *(float4*)&Vs[0][vr][c4] = *(const float4*)(Vg + (size_t)vr * QKVC + c4);
    }

    float q[16];
#pragma unroll
    for (int c = 0; c < 16; c += 4) *(float4*)&q[c] = *(const float4*)(Qg + c);

    float acc[16];
#pragma unroll
    for (int c = 0; c < 16; ++c) acc[c] = 0.f;
    float m = -INFINITY, lsum = 0.f;

    __syncthreads();

    for (int ch = 0; ch < 8; ++ch) {
        float s[SCHK];
        float cmax = -INFINITY;
#pragma unroll
        for (int j = 0; j < SCHK; ++j) {
            const float* kr = &Ks[ch * SCHK + j][l * 16];
            float d = 0.f;
#pragma unroll
            for (int c = 0; c < 16; c += 4) {
                float4 kv = *(const float4*)&kr[c];
                d = fmaf(q[c], kv.x, d); d = fmaf(q[c+1], kv.y, d);
                d = fmaf(q[c+2], kv.z, d); d = fmaf(q[c+3], kv.w, d);
            }
            // reduce partial dot across the 4-lane quad
            d += __shfl_xor(d, 1, 4);
            d += __shfl_xor(d, 2, 4);
            s[j] = d * SCALE;
            cmax = fmaxf(cmax, s[j]);
        }
        float mn   = fmaxf(m, cmax);
        float corr = __expf(m - mn);   // first chunk: exp(-inf)=0, acc already 0
        float psum = 0.f;
#pragma unroll
        for (int j = 0; j < SCHK; ++j) { s[j] = __expf(s[j] - mn); psum += s[j]; }
        lsum = lsum * corr + psum;
        m = mn;
#pragma unroll
        for (int c = 0; c < 16; ++c) acc[c] *= corr;

        // prefetch next V chunk into regs (hide HBM latency under PV)
        float4 v0, v1;
        if (ch + 1 < 8) {
            int r0 = t >> 4,         c0 = (t & 15) << 2;
            int r1 = (t + 256) >> 4;
            v0 = *(const float4*)(Vg + (size_t)((ch + 1) * SCHK + r0) * QKVC + c0);
            v1 = *(const float4*)(Vg + (size_t)((ch + 1) * SCHK + r1) * QKVC + c0);
        }
        // PV accumulate (this lane's 16-dim slice)
#pragma unroll
        for (int j = 0; j < SCHK; ++j) {
            const float* vrp = &Vs[ch & 1][j][l * 16];
            float p = s[j];
#pragma unroll
            for (int c = 0; c < 16; c += 4) {
                float4 vv = *(const float4*)&vrp[c];
                acc[c]   = fmaf(p, vv.x, acc[c]);   acc[c+1] = fmaf(p, vv.y, acc[c+1]);
                acc[c+2] = fmaf(p, vv.z, acc[c+2]); acc[c+3] = fmaf(p, vv.w, acc[c+3]);
            }
        }
        if (ch + 1 < 8) {
            int r0 = t >> 4, c0 = (t & 15) << 2;
            int r1 = (t + 256) >> 4;
            *(float4*)&Vs[(ch + 1) & 1][r0][c0] = v0;
            *(float4*)&Vs[(ch + 1) & 1][r1][c0] = v1;
        }
        __syncthreads();
    }

    float inv = 1.f / lsum;
    float* op = Out + ((size_t)(b * 4 + h) * NTOK + base + row) * DH + l * 16;
#pragma unroll
    for (int c = 0; c < 16; c += 4)
        *(float4*)(op + c) = make_float4(acc[c]*inv, acc[c+1]*inv, acc[c+2]*inv, acc[c+3]*inv);
}

// ================= Temporal attention: heads 4..7, per spatial pos over 16 frames =============
__global__ __launch_bounds__(256) void attn_temporal(const float* __restrict__ QKV,
                                                     float* __restrict__ Out) {
    const int rid   = blockIdx.x * 256 + threadIdx.x;
    const int tt    = rid & 15;
    const int s     = (rid >> 4) & 255;
    const int h     = (rid >> 12) & 3;
    const int b     = rid >> 14;
    const int head  = 4 + h;
    const int token = s * 16 + tt;
    const size_t rowoff = (size_t)b * NTOK;

    const float* Qp = QKV + (rowoff + token) * QKVC + head * DH;
    const float* Kb = QKV + (rowoff + s * 16) * QKVC + 512  + head * DH;
    const float* Vb = QKV + (rowoff + s * 16) * QKVC + 1024 + head * DH;

    float q[DH];
#pragma unroll
    for (int c = 0; c < DH; c += 4) *(float4*)&q[c] = *(const float4*)(Qp + c);

    float sc[16];
    float mx = -INFINITY;
#pragma unroll
    for (int j = 0; j < 16; ++j) {
        const float* kr = Kb + (size_t)j * QKVC;
        float d = 0.f;
#pragma unroll
        for (int c = 0; c < DH; c += 4) {
            float4 kv = *(const float4*)(kr + c);
            d = fmaf(q[c], kv.x, d); d = fmaf(q[c+1], kv.y, d);
            d = fmaf(q[c+2], kv.z, d); d = fmaf(q[c+3], kv.w, d);
        }
        sc[j] = d * SCALE;
        mx = fmaxf(mx, sc[j]);
    }
    float lsum = 0.f;
#pragma unroll
    for (int j = 0; j < 16; ++j) { sc[j] = __expf(sc[j] - mx); lsum += sc[j]; }
    float inv = 1.f / lsum;

    float acc[DH];
#pragma unroll
    for (int c = 0; c < DH; ++c) acc[c] = 0.f;
#pragma unroll
    for (int j = 0; j < 16; ++j) {
        const float* vr = Vb + (size_t)j * QKVC;
        float p = sc[j];
#pragma unroll
        for (int c = 0; c < DH; c += 4) {
            float4 vv = *(const float4*)(vr + c);
            acc[c]   = fmaf(p, vv.x, acc[c]);   acc[c+1] = fmaf(p, vv.y, acc[c+1]);
            acc[c+2] = fmaf(p, vv.z, acc[c+2]); acc[c+3] = fmaf(p, vv.w, acc[c+3]);
        }
    }
    float* op = Out + (size_t)(NBATCH * 4) * NTOK * DH
                    + ((size_t)(b * 4 + h) * NTOK + token) * DH;
#pragma unroll
    for (int c = 0; c < DH; c += 4)
        *(float4*)(op + c) = make_float4(acc[c]*inv, acc[c+1]*inv, acc[c+2]*inv, acc[c+3]*inv);
}

extern "C" void kernel_launch(void* const* d_in, const int* in_sizes, int n_in,
                              void* d_out, int out_size, void* d_ws, size_t ws_size,
                              hipStream_t stream) {
    const float* x = (const float*)d_in[0];   // [8,4096,512] fp32
    const float* w = (const float*)d_in[1];   // [512,1536]  fp32
    float* out = (float*)d_out;               // [2,8,4,4096,64] fp32
    float* qkv = (float*)d_ws;                // 8*4096*1536*4 = 192 MiB scratch

    qkv_gemm<<<dim3(256 * 12), 256, 0, stream>>>(x, w, qkv);
    attn_spatial<<<dim3(2048), 256, 0, stream>>>(qkv, out);
    attn_temporal<<<dim3(512), 256, 0, stream>>>(qkv, out);
}